// Round 2
// baseline (511.578 us; speedup 1.0000x reference)
//
#include <hip/hip_runtime.h>
#include <hip/hip_bf16.h>

#define B_   2
#define S_   2048
#define D_   2048
#define H_   16
#define KV_  4
#define KQD_ 96
#define VD_  128

typedef __attribute__((ext_vector_type(8))) short bf16x8;
typedef __attribute__((ext_vector_type(4))) short bf16x4;
typedef __attribute__((ext_vector_type(4))) float f32x4;

__device__ __forceinline__ short f2bf(float f) {
    union { float f; unsigned u; } v; v.f = f;
    unsigned r = (v.u + 0x7fffu + ((v.u >> 16) & 1u)) >> 16;
    return (short)r;
}
__device__ __forceinline__ float bf2f(short s) {
    union { unsigned u; float f; } v; v.u = ((unsigned)(unsigned short)s) << 16;
    return v.f;
}

__device__ __forceinline__ void glds16(const void* g, void* l) {
    __builtin_amdgcn_global_load_lds(
        (__attribute__((address_space(1))) void*)(g),
        (__attribute__((address_space(3))) void*)(l), 16, 0, 0);
}

// ---------------------------------------------------------------------------
// fp32 -> bf16 conversion (vectorized, one float4 per thread)
// ---------------------------------------------------------------------------
__global__ __launch_bounds__(256) void cvt_bf16(
    const float* __restrict__ s, short* __restrict__ d, int n4)
{
    int i = blockIdx.x * 256 + threadIdx.x;
    if (i >= n4) return;
    float4 v = ((const float4*)s)[i];
    bf16x4 o;
    o.x = f2bf(v.x); o.y = f2bf(v.y); o.z = f2bf(v.z); o.w = f2bf(v.w);
    ((bf16x4*)d)[i] = o;
}

// ---------------------------------------------------------------------------
// GEMM: C[M x N] = A[M x K] * W[N x K]^T   (bf16 in, fp32 acc)
// m97 structure: 128x128 tile, BK=32, 4 waves in 2x2, 4x4 MFMA accs per wave.
// OUT: 0 = bf16 row-major, 1 = bf16 transposed C^T (for V), 2 = fp32 row-major
// ---------------------------------------------------------------------------
template <int OUT>
__global__ __launch_bounds__(256) void gemm_bt(
    const short* __restrict__ A, const short* __restrict__ W,
    void* __restrict__ Cv, int M, int N, int K)
{
    __shared__ short As[128 * 32];
    __shared__ short Ws[128 * 32];

    const int tid  = threadIdx.x;
    const int wv   = tid >> 6;       // wave 0..3
    const int lane = tid & 63;
    const int wm   = wv >> 1, wn = wv & 1;
    const int m0   = blockIdx.x * 128;
    const int n0   = blockIdx.y * 128;
    const int l16  = lane & 15;
    const int qd   = lane >> 4;      // quad 0..3

    f32x4 acc[4][4] = {};

    for (int k0 = 0; k0 < K; k0 += 32) {
        __syncthreads();   // prev tile fully consumed before overwrite
#pragma unroll
        for (int r = 0; r < 2; ++r) {
            int flat = r * 256 + tid;
            int row = flat >> 2, ch = flat & 3;
            const short* ga = A + (long)(m0 + row) * K + k0 + ch * 8;
            const short* gw = W + (long)(n0 + row) * K + k0 + ch * 8;
            int base = (r * 256 + wv * 64) * 8;   // shorts (lane*16B appended by HW)
            glds16(ga, As + base);
            glds16(gw, Ws + base);
        }
        __syncthreads();   // drains vmcnt -> LDS valid

        bf16x8 af[4], wf[4];
#pragma unroll
        for (int i = 0; i < 4; ++i) {
            af[i] = *(const bf16x8*)(As + (wm * 64 + i * 16 + l16) * 32 + qd * 8);
            wf[i] = *(const bf16x8*)(Ws + (wn * 64 + i * 16 + l16) * 32 + qd * 8);
        }
#pragma unroll
        for (int i = 0; i < 4; ++i)
#pragma unroll
            for (int j = 0; j < 4; ++j)
                acc[i][j] = __builtin_amdgcn_mfma_f32_16x16x32_bf16(
                    af[i], wf[j], acc[i][j], 0, 0, 0);
    }

    if (OUT == 0) {
        short* C = (short*)Cv;
#pragma unroll
        for (int i = 0; i < 4; ++i) {
            int row0 = m0 + wm * 64 + i * 16 + qd * 4;
#pragma unroll
            for (int j = 0; j < 4; ++j) {
                int col = n0 + wn * 64 + j * 16 + l16;
#pragma unroll
                for (int r = 0; r < 4; ++r)
                    C[(long)(row0 + r) * N + col] = f2bf(acc[i][j][r]);
            }
        }
    } else if (OUT == 1) {
        short* C = (short*)Cv;
#pragma unroll
        for (int i = 0; i < 4; ++i) {
            int row0 = m0 + wm * 64 + i * 16 + qd * 4;
#pragma unroll
            for (int j = 0; j < 4; ++j) {
                int col = n0 + wn * 64 + j * 16 + l16;
                bf16x4 pk;
                pk.x = f2bf(acc[i][j][0]); pk.y = f2bf(acc[i][j][1]);
                pk.z = f2bf(acc[i][j][2]); pk.w = f2bf(acc[i][j][3]);
                *(bf16x4*)(C + (long)col * M + row0) = pk;   // C^T, 4 rows contiguous
            }
        }
    } else {
        float* C = (float*)Cv;
#pragma unroll
        for (int i = 0; i < 4; ++i) {
            int row0 = m0 + wm * 64 + i * 16 + qd * 4;
#pragma unroll
            for (int j = 0; j < 4; ++j) {
                int col = n0 + wn * 64 + j * 16 + l16;
#pragma unroll
                for (int r = 0; r < 4; ++r)
                    C[(long)(row0 + r) * N + col] = acc[i][j][r];
            }
        }
    }
}

// ---------------------------------------------------------------------------
// RMSNorm (eps=1e-6 over 96) + RoPE, in place on bf16. One wave per vector.
// Lane j<48 owns the rotate pair (j, j+48). Norm weight is fp32 (all-math fp32).
// ---------------------------------------------------------------------------
__global__ __launch_bounds__(256) void rms_rope(
    short* __restrict__ x, const float* __restrict__ w,
    const int* __restrict__ pos_ids, int nh, int nvec)
{
    int wid  = (int)((blockIdx.x * 256 + threadIdx.x) >> 6);
    int lane = threadIdx.x & 63;
    if (wid >= nvec) return;

    short* v = x + (long)wid * 96;
    float x0 = 0.f, x1 = 0.f;
    if (lane < 48) { x0 = bf2f(v[lane]); x1 = bf2f(v[lane + 48]); }
    float ss = x0 * x0 + x1 * x1;
#pragma unroll
    for (int off = 1; off < 64; off <<= 1) ss += __shfl_xor(ss, off, 64);
    float rr = rsqrtf(ss * (1.0f / 96.0f) + 1e-6f);

    if (lane < 48) {
        int pos = pos_ids[wid / nh];
        float y0 = (x0 * rr) * w[lane];
        float y1 = (x1 * rr) * w[lane + 48];
        // inv_freq = 10000^(-lane/48)
        float inv = exp2f(-(float)lane * (13.287712379549449f / 48.0f));
        float fr  = (float)pos * inv;
        float c, s;
        sincosf(fr, &s, &c);
        v[lane]      = f2bf(y0 * c - y1 * s);
        v[lane + 48] = f2bf(y1 * c + y0 * s);
    }
}

// ---------------------------------------------------------------------------
// Flash attention (causal, GQA 4:1). Block = 4 waves = 64 q rows for (b,h).
// K-tile = 64 keys. QK^T and PV with mfma 16x16x32; P via padded LDS.
// q: (B,S,H,96)  k: (B,S,KV,96)  vt: (KV*VD, B*S)  out: (B,S,H*128)  all bf16
// ---------------------------------------------------------------------------
__global__ __launch_bounds__(256) void attn(
    const short* __restrict__ q, const short* __restrict__ k,
    const short* __restrict__ vt, short* __restrict__ out)
{
    __shared__ short Ks[64 * 96];        // 12 KB, key-major (glds, unpadded)
    __shared__ short Vs[128 * 64];       // 16 KB, V^T tile: row=vd, col=key
    __shared__ short Ps[4][16 * 72];     // 9 KB, per-wave P, pad 64->72

    const int tid  = threadIdx.x;
    const int lane = tid & 63;
    const int wv   = tid >> 6;
    const int qt   = blockIdx.x;          // q-tile 0..31
    const int bh   = blockIdx.y;          // 0..31
    const int b    = bh >> 4, h = bh & 15;
    const int kvh  = h >> 2;
    const int q0   = qt * 64;
    const int l16  = lane & 15;
    const int qd   = lane >> 4;

    // Q fragments (A-operand), 16 rows x 96, loaded once
    bf16x8 qf[3];
    {
        int s = q0 + wv * 16 + l16;
        const short* qp = q + ((long)(b * S_ + s) * H_ + h) * 96 + qd * 8;
        qf[0] = *(const bf16x8*)(qp);
        qf[1] = *(const bf16x8*)(qp + 32);
        qf[2] = *(const bf16x8*)(qp + 64);
    }

    float m_i[4], l_i[4];
    f32x4 o[8] = {};
#pragma unroll
    for (int r = 0; r < 4; ++r) { m_i[r] = -1e30f; l_i[r] = 0.f; }

    for (int kt = 0; kt <= qt; ++kt) {
        const int k0 = kt * 64;
        __syncthreads();
        // stage K tile: 64 rows x 96 elems = 12 x 16B per row; 768 slots
#pragma unroll
        for (int r = 0; r < 3; ++r) {
            int flat = r * 256 + tid;
            int row = flat / 12, ch = flat % 12;
            const short* gk = k + ((long)(b * S_ + k0 + row) * KV_ + kvh) * 96 + ch * 8;
            glds16(gk, Ks + (r * 256 + wv * 64) * 8);
        }
        // stage V^T tile: 128 rows(vd) x 64 keys = 8 x 16B per row; 1024 slots
#pragma unroll
        for (int r = 0; r < 4; ++r) {
            int flat = r * 256 + tid;
            int row = flat >> 3, ch = flat & 7;
            const short* gv = vt + ((long)(kvh * 128 + row) * B_ + b) * S_ + k0 + ch * 8;
            glds16(gv, Vs + (r * 256 + wv * 64) * 8);
        }
        __syncthreads();

        // S = scale * Q K^T : 4 key sub-tiles x 3 K-chunks
        f32x4 sa[4];
#pragma unroll
        for (int j = 0; j < 4; ++j) {
            f32x4 a = {};
#pragma unroll
            for (int f = 0; f < 3; ++f) {
                bf16x8 kf = *(const bf16x8*)(Ks + (j * 16 + l16) * 96 + f * 32 + qd * 8);
                a = __builtin_amdgcn_mfma_f32_16x16x32_bf16(qf[f], kf, a, 0, 0, 0);
            }
            sa[j] = a * 0.10206207261596575f;   // 1/sqrt(96)
        }
        if (kt == qt) {   // causal mask, diagonal tile only
            int qi = wv * 16 + qd * 4;
#pragma unroll
            for (int j = 0; j < 4; ++j) {
                int kj = j * 16 + l16;
#pragma unroll
                for (int r = 0; r < 4; ++r)
                    if (kj > qi + r) sa[j][r] = -1e30f;
            }
        }

        // online softmax (rows live in 16-lane groups; reduce within group)
        float mx[4];
#pragma unroll
        for (int r = 0; r < 4; ++r)
            mx[r] = fmaxf(fmaxf(sa[0][r], sa[1][r]), fmaxf(sa[2][r], sa[3][r]));
#pragma unroll
        for (int off = 1; off < 16; off <<= 1)
#pragma unroll
            for (int r = 0; r < 4; ++r)
                mx[r] = fmaxf(mx[r], __shfl_xor(mx[r], off, 64));

        float al[4], rs[4] = {0.f, 0.f, 0.f, 0.f};
#pragma unroll
        for (int r = 0; r < 4; ++r) {
            float mn = fmaxf(m_i[r], mx[r]);
            al[r] = __expf(m_i[r] - mn);
            m_i[r] = mn;
        }
#pragma unroll
        for (int j = 0; j < 4; ++j)
#pragma unroll
            for (int r = 0; r < 4; ++r) {
                float p = __expf(sa[j][r] - m_i[r]);
                rs[r] += p;
                Ps[wv][(qd * 4 + r) * 72 + j * 16 + l16] = f2bf(p);
            }
#pragma unroll
        for (int off = 1; off < 16; off <<= 1)
#pragma unroll
            for (int r = 0; r < 4; ++r) rs[r] += __shfl_xor(rs[r], off, 64);
#pragma unroll
        for (int r = 0; r < 4; ++r) l_i[r] = l_i[r] * al[r] + rs[r];
#pragma unroll
        for (int t = 0; t < 8; ++t)
#pragma unroll
            for (int r = 0; r < 4; ++r) o[t][r] *= al[r];

        // P (A-layout) from per-wave LDS; PV over 8 vd sub-tiles x 2 K-chunks
        bf16x8 pf[2];
#pragma unroll
        for (int c = 0; c < 2; ++c)
            pf[c] = *(const bf16x8*)(&Ps[wv][l16 * 72 + c * 32 + qd * 8]);
#pragma unroll
        for (int t = 0; t < 8; ++t)
#pragma unroll
            for (int c = 0; c < 2; ++c) {
                bf16x8 vf = *(const bf16x8*)(Vs + (t * 16 + l16) * 64 + c * 32 + qd * 8);
                o[t] = __builtin_amdgcn_mfma_f32_16x16x32_bf16(pf[c], vf, o[t], 0, 0, 0);
            }
    }

    // epilogue: O / l, write (B,S,H*128) bf16
#pragma unroll
    for (int t = 0; t < 8; ++t)
#pragma unroll
        for (int r = 0; r < 4; ++r) {
            int s = q0 + wv * 16 + qd * 4 + r;
            out[((long)(b * S_ + s) * H_ + h) * 128 + t * 16 + l16] =
                f2bf(o[t][r] / l_i[r]);
        }
}

// ---------------------------------------------------------------------------
extern "C" void kernel_launch(void* const* d_in, const int* in_sizes, int n_in,
                              void* d_out, int out_size, void* d_ws, size_t ws_size,
                              hipStream_t stream)
{
    const float* hs  = (const float*)d_in[0];
    const int*   pos = (const int*)d_in[1];
    const float* Wq  = (const float*)d_in[2];
    const float* Wk  = (const float*)d_in[3];
    const float* Wv  = (const float*)d_in[4];
    const float* Wo  = (const float*)d_in[5];
    const float* qnw = (const float*)d_in[6];
    const float* knw = (const float*)d_in[7];
    float* out = (float*)d_out;
    short* ws  = (short*)d_ws;

    const int M = B_ * S_;                        // 4096

    // bf16 copies of inputs
    short* hsb = ws;                              // M x 2048
    short* Wqb = hsb + (long)M * D_;              // 1536 x 2048
    short* Wkb = Wqb + (long)H_ * KQD_ * D_;      // 384 x 2048
    short* Wvb = Wkb + (long)KV_ * KQD_ * D_;     // 512 x 2048
    short* Wob = Wvb + (long)KV_ * VD_ * D_;      // 2048 x 2048
    // intermediates
    short* q_ws  = Wob + (long)D_ * H_ * VD_;     // M x 1536
    short* k_ws  = q_ws + (long)M * H_ * KQD_;    // M x 384
    short* vt_ws = k_ws + (long)M * KV_ * KQD_;   // 512 x M  (V^T)
    short* ao_ws = vt_ws + (long)KV_ * VD_ * M;   // M x 2048

    auto cvt = [&](const float* src, short* dst, long n) {
        int n4 = (int)(n / 4);
        cvt_bf16<<<(n4 + 255) / 256, 256, 0, stream>>>(src, dst, n4);
    };
    cvt(hs, hsb, (long)M * D_);
    cvt(Wq, Wqb, (long)H_ * KQD_ * D_);
    cvt(Wk, Wkb, (long)KV_ * KQD_ * D_);
    cvt(Wv, Wvb, (long)KV_ * VD_ * D_);
    cvt(Wo, Wob, (long)D_ * H_ * VD_);

    gemm_bt<0><<<dim3(M / 128, (H_ * KQD_) / 128), 256, 0, stream>>>(
        hsb, Wqb, q_ws, M, H_ * KQD_, D_);
    gemm_bt<0><<<dim3(M / 128, (KV_ * KQD_) / 128), 256, 0, stream>>>(
        hsb, Wkb, k_ws, M, KV_ * KQD_, D_);
    gemm_bt<1><<<dim3(M / 128, (KV_ * VD_) / 128), 256, 0, stream>>>(
        hsb, Wvb, vt_ws, M, KV_ * VD_, D_);

    rms_rope<<<(M * H_) / 4, 256, 0, stream>>>(q_ws, qnw, pos, H_, M * H_);
    rms_rope<<<(M * KV_) / 4, 256, 0, stream>>>(k_ws, knw, pos, KV_, M * KV_);

    attn<<<dim3(S_ / 64, B_ * H_), 256, 0, stream>>>(q_ws, k_ws, vt_ws, ao_ws);

    gemm_bt<2><<<dim3(M / 128, D_ / 128), 256, 0, stream>>>(
        ao_ws, Wob, (void*)out, M, D_, H_ * VD_);
}

// Round 3
// 446.228 us; speedup vs baseline: 1.1464x; 1.1464x over previous
//
#include <hip/hip_runtime.h>
#include <hip/hip_bf16.h>

#define B_   2
#define S_   2048
#define D_   2048
#define H_   16
#define KV_  4
#define KQD_ 96
#define VD_  128
#define NQK_ 1920            // H*KQD + KV*KQD = 1536 + 384
#define M_   4096            // B*S

typedef __attribute__((ext_vector_type(8))) short bf16x8;
typedef __attribute__((ext_vector_type(4))) short bf16x4;
typedef __attribute__((ext_vector_type(4))) float f32x4;

__device__ __forceinline__ short f2bf(float f) {
    union { float f; unsigned u; } v; v.f = f;
    unsigned r = (v.u + 0x7fffu + ((v.u >> 16) & 1u)) >> 16;
    return (short)r;
}
__device__ __forceinline__ float bf2f(short s) {
    union { unsigned u; float f; } v; v.u = ((unsigned)(unsigned short)s) << 16;
    return v.f;
}

__device__ __forceinline__ void glds16(const void* g, void* l) {
    __builtin_amdgcn_global_load_lds(
        (__attribute__((address_space(1))) void*)(g),
        (__attribute__((address_space(3))) void*)(l), 16, 0, 0);
}

// ---------------------------------------------------------------------------
// fp32 -> bf16 for all five inputs in one launch; dests are contiguous in ws.
// float4-unit boundaries: hs 2097152 | Wq 786432 | Wk 196608 | Wv 262144 | Wo 1048576
// ---------------------------------------------------------------------------
__global__ __launch_bounds__(256) void cvt_all(
    const float* __restrict__ hs, const float* __restrict__ wq,
    const float* __restrict__ wk, const float* __restrict__ wv,
    const float* __restrict__ wo, short* __restrict__ dst)
{
    int i = blockIdx.x * 256 + threadIdx.x;
    if (i >= 4390912) return;
    const float* s; int off;
    if      (i < 2097152) { s = hs; off = i; }
    else if (i < 2883584) { s = wq; off = i - 2097152; }
    else if (i < 3080192) { s = wk; off = i - 2883584; }
    else if (i < 3342336) { s = wv; off = i - 3080192; }
    else                  { s = wo; off = i - 3342336; }
    float4 v = ((const float4*)s)[off];
    bf16x4 o;
    o.x = f2bf(v.x); o.y = f2bf(v.y); o.z = f2bf(v.z); o.w = f2bf(v.w);
    ((bf16x4*)dst)[i] = o;
}

// ---------------------------------------------------------------------------
// GEMM: C[M x N] = A[M x K] * W[N x K]^T   (bf16 in, fp32 acc)
// m97 structure: 128x128 tile, BK=32, 4 waves 2x2, 4x4 MFMA accs.
// OUT==2: fp32 row-major (final output).  OUT==3: fused QKV — cols < NQK_ go
// row-major (stride NQK_) into Cv; cols >= NQK_ store transposed into Cv2
// (V^T layout, (KV*VD) x M). n-tiles are 128-wide and NQK_=15*128, so each
// block is entirely one side.
// ---------------------------------------------------------------------------
template <int OUT>
__global__ __launch_bounds__(256) void gemm_bt(
    const short* __restrict__ A, const short* __restrict__ W,
    void* __restrict__ Cv, void* __restrict__ Cv2, int M, int N, int K)
{
    __shared__ short As[128 * 32];
    __shared__ short Ws[128 * 32];

    const int tid  = threadIdx.x;
    const int wv   = tid >> 6;
    const int lane = tid & 63;
    const int wm   = wv >> 1, wn = wv & 1;
    const int m0   = blockIdx.x * 128;
    const int n0   = blockIdx.y * 128;
    const int l16  = lane & 15;
    const int qd   = lane >> 4;

    f32x4 acc[4][4] = {};

    for (int k0 = 0; k0 < K; k0 += 32) {
        __syncthreads();
#pragma unroll
        for (int r = 0; r < 2; ++r) {
            int flat = r * 256 + tid;
            int row = flat >> 2, ch = flat & 3;
            const short* ga = A + (long)(m0 + row) * K + k0 + ch * 8;
            const short* gw = W + (long)(n0 + row) * K + k0 + ch * 8;
            int base = (r * 256 + wv * 64) * 8;
            glds16(ga, As + base);
            glds16(gw, Ws + base);
        }
        __syncthreads();

        bf16x8 af[4], wf[4];
#pragma unroll
        for (int i = 0; i < 4; ++i) {
            af[i] = *(const bf16x8*)(As + (wm * 64 + i * 16 + l16) * 32 + qd * 8);
            wf[i] = *(const bf16x8*)(Ws + (wn * 64 + i * 16 + l16) * 32 + qd * 8);
        }
#pragma unroll
        for (int i = 0; i < 4; ++i)
#pragma unroll
            for (int j = 0; j < 4; ++j)
                acc[i][j] = __builtin_amdgcn_mfma_f32_16x16x32_bf16(
                    af[i], wf[j], acc[i][j], 0, 0, 0);
    }

    if (OUT == 2) {
        float* C = (float*)Cv;
#pragma unroll
        for (int i = 0; i < 4; ++i) {
            int row0 = m0 + wm * 64 + i * 16 + qd * 4;
#pragma unroll
            for (int j = 0; j < 4; ++j) {
                int col = n0 + wn * 64 + j * 16 + l16;
#pragma unroll
                for (int r = 0; r < 4; ++r)
                    C[(long)(row0 + r) * N + col] = acc[i][j][r];
            }
        }
    } else {  // OUT == 3
        if (n0 < NQK_) {
            short* C = (short*)Cv;
#pragma unroll
            for (int i = 0; i < 4; ++i) {
                int row0 = m0 + wm * 64 + i * 16 + qd * 4;
#pragma unroll
                for (int j = 0; j < 4; ++j) {
                    int col = n0 + wn * 64 + j * 16 + l16;
#pragma unroll
                    for (int r = 0; r < 4; ++r)
                        C[(long)(row0 + r) * NQK_ + col] = f2bf(acc[i][j][r]);
                }
            }
        } else {
            short* C = (short*)Cv2;
#pragma unroll
            for (int i = 0; i < 4; ++i) {
                int row0 = m0 + wm * 64 + i * 16 + qd * 4;
#pragma unroll
                for (int j = 0; j < 4; ++j) {
                    int vcol = n0 - NQK_ + wn * 64 + j * 16 + l16;
                    bf16x4 pk;
                    pk.x = f2bf(acc[i][j][0]); pk.y = f2bf(acc[i][j][1]);
                    pk.z = f2bf(acc[i][j][2]); pk.w = f2bf(acc[i][j][3]);
                    *(bf16x4*)(C + (long)vcol * M_ + row0) = pk;  // V^T
                }
            }
        }
    }
}

// ---------------------------------------------------------------------------
// RMSNorm + RoPE for q and k in one launch, in place on fused qk buffer
// (row stride NQK_; q at col h*96, k at col 1536 + kvh*96). One wave/vector.
// ---------------------------------------------------------------------------
__global__ __launch_bounds__(256) void rms_rope(
    short* __restrict__ qk, const float* __restrict__ qw,
    const float* __restrict__ kw, const int* __restrict__ pos_ids)
{
    int wid  = (int)((blockIdx.x * 256 + threadIdx.x) >> 6);
    int lane = threadIdx.x & 63;

    short* v; const float* w; int row;
    if (wid < 65536) {                       // q: 4096 rows x 16 heads
        row = wid >> 4;
        v = qk + (long)row * NQK_ + (wid & 15) * 96;
        w = qw;
    } else {                                 // k: 4096 rows x 4 heads
        int t = wid - 65536;
        row = t >> 2;
        v = qk + (long)row * NQK_ + 1536 + (t & 3) * 96;
        w = kw;
    }

    float x0 = 0.f, x1 = 0.f;
    if (lane < 48) { x0 = bf2f(v[lane]); x1 = bf2f(v[lane + 48]); }
    float ss = x0 * x0 + x1 * x1;
#pragma unroll
    for (int off = 1; off < 64; off <<= 1) ss += __shfl_xor(ss, off, 64);
    float rr = rsqrtf(ss * (1.0f / 96.0f) + 1e-6f);

    if (lane < 48) {
        int pos = pos_ids[row];
        float y0 = (x0 * rr) * w[lane];
        float y1 = (x1 * rr) * w[lane + 48];
        float inv = exp2f(-(float)lane * (13.287712379549449f / 48.0f));
        float fr  = (float)pos * inv;
        float c, s;
        sincosf(fr, &s, &c);
        v[lane]      = f2bf(y0 * c - y1 * s);
        v[lane + 48] = f2bf(y1 * c + y0 * s);
    }
}

// ---------------------------------------------------------------------------
// Flash attention (causal, GQA 4:1). Block = 4 waves = 64 q rows. K-tile=64.
// Padded LDS (Ks stride 104, Vs/Ps stride 72 -> <=2-way bank aliasing = free).
// Next K/V tile register-prefetched during compute. Big q-tiles launch first.
// qk: fused (M x NQK_)  vt: (KV*VD x M)  out: (B,S,H*128) bf16
// ---------------------------------------------------------------------------
__global__ __launch_bounds__(256) void attn(
    const short* __restrict__ qk, const short* __restrict__ vt,
    short* __restrict__ out)
{
    __shared__ short Ks[64 * 104];       // 13.0 KB
    __shared__ short Vs[128 * 72];       // 18.0 KB
    __shared__ short Ps[4][16 * 72];     //  9.0 KB   (40 KB total -> 4 blocks/CU)

    const int tid  = threadIdx.x;
    const int lane = tid & 63;
    const int wv   = tid >> 6;
    const int qt   = (int)gridDim.x - 1 - (int)blockIdx.x;  // big tiles first
    const int bh   = blockIdx.y;
    const int b    = bh >> 4, h = bh & 15;
    const int kvh  = h >> 2;
    const int q0   = qt * 64;
    const int l16  = lane & 15;
    const int qd   = lane >> 4;
    const long bS  = (long)b * S_;

    // Q fragments (A-operand), 16 rows x 96
    bf16x8 qf[3];
    {
        int s = q0 + wv * 16 + l16;
        const short* qp = qk + (bS + s) * NQK_ + h * 96 + qd * 8;
        qf[0] = *(const bf16x8*)(qp);
        qf[1] = *(const bf16x8*)(qp + 32);
        qf[2] = *(const bf16x8*)(qp + 64);
    }

    const short* kbase = qk + bS * NQK_ + 1536 + kvh * 96;
    const short* vbase = vt + (long)kvh * 128 * (B_ * S_) + bS;

    auto loadK = [&](int k0, bf16x8* kr) {
#pragma unroll
        for (int r = 0; r < 3; ++r) {
            int flat = r * 256 + tid;
            int row = flat / 12, ch = flat % 12;
            kr[r] = *(const bf16x8*)(kbase + (long)(k0 + row) * NQK_ + ch * 8);
        }
    };
    auto loadV = [&](int k0, bf16x8* vr) {
#pragma unroll
        for (int r = 0; r < 4; ++r) {
            int flat = r * 256 + tid;
            int row = flat >> 3, ch = flat & 7;
            vr[r] = *(const bf16x8*)(vbase + (long)row * (B_ * S_) + k0 + ch * 8);
        }
    };
    auto storeKV = [&](bf16x8* kr, bf16x8* vr) {
#pragma unroll
        for (int r = 0; r < 3; ++r) {
            int flat = r * 256 + tid;
            int row = flat / 12, ch = flat % 12;
            *(bf16x8*)(Ks + row * 104 + ch * 8) = kr[r];
        }
#pragma unroll
        for (int r = 0; r < 4; ++r) {
            int flat = r * 256 + tid;
            int row = flat >> 3, ch = flat & 7;
            *(bf16x8*)(Vs + row * 72 + ch * 8) = vr[r];
        }
    };

    {
        bf16x8 kr[3], vr[4];
        loadK(0, kr); loadV(0, vr);
        storeKV(kr, vr);
    }
    __syncthreads();

    float m_i[4], l_i[4];
    f32x4 o[8] = {};
#pragma unroll
    for (int r = 0; r < 4; ++r) { m_i[r] = -1e30f; l_i[r] = 0.f; }

    for (int kt = 0; kt <= qt; ++kt) {
        const bool more = (kt < qt);
        bf16x8 kn[3], vn[4];
        if (more) { loadK((kt + 1) * 64, kn); loadV((kt + 1) * 64, vn); }

        // S = scale * Q K^T
        f32x4 sa[4];
#pragma unroll
        for (int j = 0; j < 4; ++j) {
            f32x4 a = {};
#pragma unroll
            for (int f = 0; f < 3; ++f) {
                bf16x8 kf = *(const bf16x8*)(Ks + (j * 16 + l16) * 104 + f * 32 + qd * 8);
                a = __builtin_amdgcn_mfma_f32_16x16x32_bf16(qf[f], kf, a, 0, 0, 0);
            }
            sa[j] = a * 0.10206207261596575f;   // 1/sqrt(96)
        }
        if (kt == qt) {   // causal mask, diagonal tile only
            int qi = wv * 16 + qd * 4;
#pragma unroll
            for (int j = 0; j < 4; ++j) {
                int kj = j * 16 + l16;
#pragma unroll
                for (int r = 0; r < 4; ++r)
                    if (kj > qi + r) sa[j][r] = -1e30f;
            }
        }

        // online softmax (rows in 16-lane groups)
        float mx[4];
#pragma unroll
        for (int r = 0; r < 4; ++r)
            mx[r] = fmaxf(fmaxf(sa[0][r], sa[1][r]), fmaxf(sa[2][r], sa[3][r]));
#pragma unroll
        for (int off = 1; off < 16; off <<= 1)
#pragma unroll
            for (int r = 0; r < 4; ++r)
                mx[r] = fmaxf(mx[r], __shfl_xor(mx[r], off, 64));

        float al[4], rs[4] = {0.f, 0.f, 0.f, 0.f};
#pragma unroll
        for (int r = 0; r < 4; ++r) {
            float mn = fmaxf(m_i[r], mx[r]);
            al[r] = __expf(m_i[r] - mn);
            m_i[r] = mn;
        }
#pragma unroll
        for (int j = 0; j < 4; ++j)
#pragma unroll
            for (int r = 0; r < 4; ++r) {
                float p = __expf(sa[j][r] - m_i[r]);
                rs[r] += p;
                Ps[wv][(qd * 4 + r) * 72 + j * 16 + l16] = f2bf(p);
            }
#pragma unroll
        for (int off = 1; off < 16; off <<= 1)
#pragma unroll
            for (int r = 0; r < 4; ++r) rs[r] += __shfl_xor(rs[r], off, 64);
#pragma unroll
        for (int r = 0; r < 4; ++r) l_i[r] = l_i[r] * al[r] + rs[r];
#pragma unroll
        for (int t = 0; t < 8; ++t)
#pragma unroll
            for (int r = 0; r < 4; ++r) o[t][r] *= al[r];

        // PV: P (A-layout) from per-wave LDS, V^T tile from Vs
        bf16x8 pf[2];
#pragma unroll
        for (int c = 0; c < 2; ++c)
            pf[c] = *(const bf16x8*)(&Ps[wv][l16 * 72 + c * 32 + qd * 8]);
#pragma unroll
        for (int t = 0; t < 8; ++t)
#pragma unroll
            for (int c = 0; c < 2; ++c) {
                bf16x8 vf = *(const bf16x8*)(Vs + (t * 16 + l16) * 72 + c * 32 + qd * 8);
                o[t] = __builtin_amdgcn_mfma_f32_16x16x32_bf16(pf[c], vf, o[t], 0, 0, 0);
            }

        if (more) {
            __syncthreads();          // all LDS reads of tile kt complete
            storeKV(kn, vn);
            __syncthreads();          // tile kt+1 visible
        }
    }

    // epilogue: O / l
#pragma unroll
    for (int t = 0; t < 8; ++t)
#pragma unroll
        for (int r = 0; r < 4; ++r) {
            int s = q0 + wv * 16 + qd * 4 + r;
            out[((bS + s) * H_ + h) * 128 + t * 16 + l16] =
                f2bf(o[t][r] / l_i[r]);
        }
}

// ---------------------------------------------------------------------------
extern "C" void kernel_launch(void* const* d_in, const int* in_sizes, int n_in,
                              void* d_out, int out_size, void* d_ws, size_t ws_size,
                              hipStream_t stream)
{
    const float* hs  = (const float*)d_in[0];
    const int*   pos = (const int*)d_in[1];
    const float* Wq  = (const float*)d_in[2];
    const float* Wk  = (const float*)d_in[3];
    const float* Wv  = (const float*)d_in[4];
    const float* Wo  = (const float*)d_in[5];
    const float* qnw = (const float*)d_in[6];
    const float* knw = (const float*)d_in[7];
    float* out = (float*)d_out;
    short* ws  = (short*)d_ws;

    // bf16 copies (contiguous: hsb | Wqb | Wkb | Wvb | Wob)
    short* hsb   = ws;                         // 4096 x 2048
    short* Wqkvb = hsb + (long)M_ * D_;        // 2432 x 2048 (Wq|Wk|Wv rows)
    short* Wob   = Wqkvb + (long)2432 * D_;    // 2048 x 2048
    short* qk_ws = Wob + (long)D_ * 2048;      // 4096 x 1920 (q | k fused)
    short* vt_ws = qk_ws + (long)M_ * NQK_;    // 512 x 4096  (V^T)
    short* ao_ws = vt_ws + (long)512 * M_;     // 4096 x 2048

    cvt_all<<<17152, 256, 0, stream>>>(hs, Wq, Wk, Wv, Wo, ws);

    // fused QKV projection: N = 1536+384+512 = 2432
    gemm_bt<3><<<dim3(M_ / 128, 2432 / 128), 256, 0, stream>>>(
        hsb, Wqkvb, qk_ws, vt_ws, M_, 2432, D_);

    rms_rope<<<(65536 + 16384) / 4, 256, 0, stream>>>(qk_ws, qnw, knw, pos);

    attn<<<dim3(S_ / 64, B_ * H_), 256, 0, stream>>>(qk_ws, vt_ws, ao_ws);

    gemm_bt<2><<<dim3(M_ / 128, D_ / 128), 256, 0, stream>>>(
        ao_ws, Wob, (void*)out, nullptr, M_, D_, H_ * VD_);
}

// Round 4
// 368.931 us; speedup vs baseline: 1.3866x; 1.2095x over previous
//
#include <hip/hip_runtime.h>
#include <hip/hip_bf16.h>

#define B_   2
#define S_   2048
#define D_   2048
#define H_   16
#define KV_  4
#define KQD_ 96
#define VD_  128
#define NQK_ 1920            // H*KQD + KV*KQD = 1536 + 384
#define M_   4096            // B*S

typedef __attribute__((ext_vector_type(8))) short bf16x8;
typedef __attribute__((ext_vector_type(4))) short bf16x4;
typedef __attribute__((ext_vector_type(4))) float f32x4;

__device__ __forceinline__ short f2bf(float f) {
    union { float f; unsigned u; } v; v.f = f;
    unsigned r = (v.u + 0x7fffu + ((v.u >> 16) & 1u)) >> 16;
    return (short)r;
}
__device__ __forceinline__ float bf2f(short s) {
    union { unsigned u; float f; } v; v.u = ((unsigned)(unsigned short)s) << 16;
    return v.f;
}

__device__ __forceinline__ void glds16(const void* g, void* l) {
    __builtin_amdgcn_global_load_lds(
        (__attribute__((address_space(1))) void*)(g),
        (__attribute__((address_space(3))) void*)(l), 16, 0, 0);
}

// DPP-based 16-lane reductions (no LDS/ds_swizzle traffic)
template <int CTRL>
__device__ __forceinline__ float dppf(float x) {
    return __int_as_float(__builtin_amdgcn_update_dpp(
        0, __float_as_int(x), CTRL, 0xF, 0xF, true));
}
__device__ __forceinline__ float rmax16(float x) {
    x = fmaxf(x, dppf<0xB1>(x));    // quad_perm [1,0,3,2]  (xor 1)
    x = fmaxf(x, dppf<0x4E>(x));    // quad_perm [2,3,0,1]  (xor 2)
    x = fmaxf(x, dppf<0x124>(x));   // row_ror:4
    x = fmaxf(x, dppf<0x128>(x));   // row_ror:8
    return x;
}
__device__ __forceinline__ float rsum16(float x) {
    x += dppf<0xB1>(x);
    x += dppf<0x4E>(x);
    x += dppf<0x124>(x);
    x += dppf<0x128>(x);
    return x;
}

// ---------------------------------------------------------------------------
// fp32 -> bf16 for all five inputs in one launch; dests contiguous in ws.
// ---------------------------------------------------------------------------
__global__ __launch_bounds__(256) void cvt_all(
    const float* __restrict__ hs, const float* __restrict__ wq,
    const float* __restrict__ wk, const float* __restrict__ wv,
    const float* __restrict__ wo, short* __restrict__ dst)
{
    int i = blockIdx.x * 256 + threadIdx.x;
    if (i >= 4390912) return;
    const float* s; int off;
    if      (i < 2097152) { s = hs; off = i; }
    else if (i < 2883584) { s = wq; off = i - 2097152; }
    else if (i < 3080192) { s = wk; off = i - 2883584; }
    else if (i < 3342336) { s = wv; off = i - 3080192; }
    else                  { s = wo; off = i - 3342336; }
    float4 v = ((const float4*)s)[off];
    bf16x4 o;
    o.x = f2bf(v.x); o.y = f2bf(v.y); o.z = f2bf(v.z); o.w = f2bf(v.w);
    ((bf16x4*)dst)[i] = o;
}

// ---------------------------------------------------------------------------
// GEMM: C[M x N] = A[M x K] * W[N x K]^T   (bf16 in, fp32 acc)
// OUT==2: fp32 row-major.  OUT==3: fused QKV (cols<NQK_ row-major into Cv,
// cols>=NQK_ transposed V^T into Cv2).
// ---------------------------------------------------------------------------
template <int OUT>
__global__ __launch_bounds__(256) void gemm_bt(
    const short* __restrict__ A, const short* __restrict__ W,
    void* __restrict__ Cv, void* __restrict__ Cv2, int M, int N, int K)
{
    __shared__ short As[128 * 32];
    __shared__ short Ws[128 * 32];

    const int tid  = threadIdx.x;
    const int wv   = tid >> 6;
    const int lane = tid & 63;
    const int wm   = wv >> 1, wn = wv & 1;
    const int m0   = blockIdx.x * 128;
    const int n0   = blockIdx.y * 128;
    const int l16  = lane & 15;
    const int qd   = lane >> 4;

    f32x4 acc[4][4] = {};

    for (int k0 = 0; k0 < K; k0 += 32) {
        __syncthreads();
#pragma unroll
        for (int r = 0; r < 2; ++r) {
            int flat = r * 256 + tid;
            int row = flat >> 2, ch = flat & 3;
            const short* ga = A + (long)(m0 + row) * K + k0 + ch * 8;
            const short* gw = W + (long)(n0 + row) * K + k0 + ch * 8;
            int base = (r * 256 + wv * 64) * 8;
            glds16(ga, As + base);
            glds16(gw, Ws + base);
        }
        __syncthreads();

        bf16x8 af[4], wf[4];
#pragma unroll
        for (int i = 0; i < 4; ++i) {
            af[i] = *(const bf16x8*)(As + (wm * 64 + i * 16 + l16) * 32 + qd * 8);
            wf[i] = *(const bf16x8*)(Ws + (wn * 64 + i * 16 + l16) * 32 + qd * 8);
        }
#pragma unroll
        for (int i = 0; i < 4; ++i)
#pragma unroll
            for (int j = 0; j < 4; ++j)
                acc[i][j] = __builtin_amdgcn_mfma_f32_16x16x32_bf16(
                    af[i], wf[j], acc[i][j], 0, 0, 0);
    }

    if (OUT == 2) {
        float* C = (float*)Cv;
#pragma unroll
        for (int i = 0; i < 4; ++i) {
            int row0 = m0 + wm * 64 + i * 16 + qd * 4;
#pragma unroll
            for (int j = 0; j < 4; ++j) {
                int col = n0 + wn * 64 + j * 16 + l16;
#pragma unroll
                for (int r = 0; r < 4; ++r)
                    C[(long)(row0 + r) * N + col] = acc[i][j][r];
            }
        }
    } else {  // OUT == 3
        if (n0 < NQK_) {
            short* C = (short*)Cv;
#pragma unroll
            for (int i = 0; i < 4; ++i) {
                int row0 = m0 + wm * 64 + i * 16 + qd * 4;
#pragma unroll
                for (int j = 0; j < 4; ++j) {
                    int col = n0 + wn * 64 + j * 16 + l16;
#pragma unroll
                    for (int r = 0; r < 4; ++r)
                        C[(long)(row0 + r) * NQK_ + col] = f2bf(acc[i][j][r]);
                }
            }
        } else {
            short* C = (short*)Cv2;
#pragma unroll
            for (int i = 0; i < 4; ++i) {
                int row0 = m0 + wm * 64 + i * 16 + qd * 4;
#pragma unroll
                for (int j = 0; j < 4; ++j) {
                    int vcol = n0 - NQK_ + wn * 64 + j * 16 + l16;
                    bf16x4 pk;
                    pk.x = f2bf(acc[i][j][0]); pk.y = f2bf(acc[i][j][1]);
                    pk.z = f2bf(acc[i][j][2]); pk.w = f2bf(acc[i][j][3]);
                    *(bf16x4*)(C + (long)vcol * M_ + row0) = pk;  // V^T
                }
            }
        }
    }
}

// ---------------------------------------------------------------------------
// RMSNorm + RoPE, in place on fused qk buffer (row stride NQK_).
// Q is additionally pre-scaled by (1/sqrt(96))*log2(e) so attention scores
// land directly in the exp2 domain.
// ---------------------------------------------------------------------------
__global__ __launch_bounds__(256) void rms_rope(
    short* __restrict__ qk, const float* __restrict__ qw,
    const float* __restrict__ kw, const int* __restrict__ pos_ids)
{
    int wid  = (int)((blockIdx.x * 256 + threadIdx.x) >> 6);
    int lane = threadIdx.x & 63;

    short* v; const float* w; int row; float qs;
    if (wid < 65536) {                       // q: 4096 rows x 16 heads
        row = wid >> 4;
        v = qk + (long)row * NQK_ + (wid & 15) * 96;
        w = qw;
        qs = 0.14724444f;                    // (1/sqrt(96)) * log2(e)
    } else {                                 // k: 4096 rows x 4 heads
        int t = wid - 65536;
        row = t >> 2;
        v = qk + (long)row * NQK_ + 1536 + (t & 3) * 96;
        w = kw;
        qs = 1.0f;
    }

    float x0 = 0.f, x1 = 0.f;
    if (lane < 48) { x0 = bf2f(v[lane]); x1 = bf2f(v[lane + 48]); }
    float ss = x0 * x0 + x1 * x1;
#pragma unroll
    for (int off = 1; off < 64; off <<= 1) ss += __shfl_xor(ss, off, 64);
    float rr = rsqrtf(ss * (1.0f / 96.0f) + 1e-6f);

    if (lane < 48) {
        int pos = pos_ids[row];
        float y0 = (x0 * rr) * w[lane] * qs;
        float y1 = (x1 * rr) * w[lane + 48] * qs;
        float inv = exp2f(-(float)lane * (13.287712379549449f / 48.0f));
        float fr  = (float)pos * inv;
        float c, s;
        sincosf(fr, &s, &c);
        v[lane]      = f2bf(y0 * c - y1 * s);
        v[lane + 48] = f2bf(y1 * c + y0 * s);
    }
}

// ---------------------------------------------------------------------------
// Flash attention (causal, GQA 4:1). Triangle-paired q-tiles: block pair i
// handles qt = 31-i then qt = i  ->  every block = exactly 33 k-tile units.
// Double-buffered K/V LDS (1 barrier/k-tile), DPP softmax reductions,
// exp2-domain softmax (Q pre-scaled).
// qk: fused (M x NQK_)  vt: (KV*VD x M)  out: (B,S,H*128) bf16
// ---------------------------------------------------------------------------
__global__ __launch_bounds__(256) void attn(
    const short* __restrict__ qk, const short* __restrict__ vt,
    short* __restrict__ out)
{
    __shared__ short Ks[2][64 * 104];    // 26.0 KB
    __shared__ short Vs[2][128 * 72];    // 36.0 KB
    __shared__ short Ps[4][16 * 72];     //  9.0 KB   (71 KB -> 2 blocks/CU)

    const int tid  = threadIdx.x;
    const int lane = tid & 63;
    const int wv   = tid >> 6;
    const int pair = blockIdx.x;          // 0..15
    const int bh   = blockIdx.y;          // 0..31
    const int b    = bh >> 4, h = bh & 15;
    const int kvh  = h >> 2;
    const int l16  = lane & 15;
    const int qd   = lane >> 4;
    const long bS  = (long)b * S_;

    const short* kbase = qk + bS * NQK_ + 1536 + kvh * 96;
    const short* vbase = vt + (long)kvh * 128 * (B_ * S_) + bS;

    auto loadK = [&](int k0, bf16x8* kr) {
#pragma unroll
        for (int r = 0; r < 3; ++r) {
            int flat = r * 256 + tid;
            int row = flat / 12, ch = flat % 12;
            kr[r] = *(const bf16x8*)(kbase + (long)(k0 + row) * NQK_ + ch * 8);
        }
    };
    auto loadV = [&](int k0, bf16x8* vr) {
#pragma unroll
        for (int r = 0; r < 4; ++r) {
            int flat = r * 256 + tid;
            int row = flat >> 3, ch = flat & 7;
            vr[r] = *(const bf16x8*)(vbase + (long)row * (B_ * S_) + k0 + ch * 8);
        }
    };
    auto storeKV = [&](int buf, bf16x8* kr, bf16x8* vr) {
#pragma unroll
        for (int r = 0; r < 3; ++r) {
            int flat = r * 256 + tid;
            int row = flat / 12, ch = flat % 12;
            *(bf16x8*)(Ks[buf] + row * 104 + ch * 8) = kr[r];
        }
#pragma unroll
        for (int r = 0; r < 4; ++r) {
            int flat = r * 256 + tid;
            int row = flat >> 3, ch = flat & 7;
            *(bf16x8*)(Vs[buf] + row * 72 + ch * 8) = vr[r];
        }
    };

#pragma unroll 1
    for (int pass = 0; pass < 2; ++pass) {
        const int qt = pass == 0 ? (31 - pair) : pair;
        const int q0 = qt * 64;

        // Q fragments (A-operand), 16 rows x 96 (pre-scaled by scale*log2e)
        bf16x8 qf[3];
        {
            int s = q0 + wv * 16 + l16;
            const short* qp = qk + (bS + s) * NQK_ + h * 96 + qd * 8;
            qf[0] = *(const bf16x8*)(qp);
            qf[1] = *(const bf16x8*)(qp + 32);
            qf[2] = *(const bf16x8*)(qp + 64);
        }

        float m_i[4], l_i[4];
        f32x4 o[8] = {};
#pragma unroll
        for (int r = 0; r < 4; ++r) { m_i[r] = -1e30f; l_i[r] = 0.f; }

        // prologue: tile 0 -> buf 0
        {
            bf16x8 kr[3], vr[4];
            loadK(0, kr); loadV(0, vr);
            __syncthreads();          // prior pass's LDS reads complete
            storeKV(0, kr, vr);
            __syncthreads();
        }

        for (int kt = 0; kt <= qt; ++kt) {
            const int buf = kt & 1;
            const bool more = (kt < qt);
            bf16x8 kn[3], vn[4];
            if (more) { loadK((kt + 1) * 64, kn); loadV((kt + 1) * 64, vn); }

            // S (already in exp2 domain): Q K^T
            f32x4 sa[4];
#pragma unroll
            for (int j = 0; j < 4; ++j) {
                f32x4 a = {};
#pragma unroll
                for (int f = 0; f < 3; ++f) {
                    bf16x8 kf = *(const bf16x8*)(Ks[buf] + (j * 16 + l16) * 104 + f * 32 + qd * 8);
                    a = __builtin_amdgcn_mfma_f32_16x16x32_bf16(qf[f], kf, a, 0, 0, 0);
                }
                sa[j] = a;
            }
            if (kt == qt) {   // causal mask, diagonal tile only
                int qi = wv * 16 + qd * 4;
#pragma unroll
                for (int j = 0; j < 4; ++j) {
                    int kj = j * 16 + l16;
#pragma unroll
                    for (int r = 0; r < 4; ++r)
                        if (kj > qi + r) sa[j][r] = -30000.0f;
                }
            }

            // online softmax, DPP reductions over the 16-lane row groups
            float al[4], rs[4];
#pragma unroll
            for (int r = 0; r < 4; ++r) {
                float mx = rmax16(fmaxf(fmaxf(sa[0][r], sa[1][r]),
                                        fmaxf(sa[2][r], sa[3][r])));
                float mn = fmaxf(m_i[r], mx);
                al[r] = exp2f(m_i[r] - mn);
                m_i[r] = mn;
            }
#pragma unroll
            for (int r = 0; r < 4; ++r) rs[r] = 0.f;
#pragma unroll
            for (int j = 0; j < 4; ++j)
#pragma unroll
                for (int r = 0; r < 4; ++r) {
                    float p = exp2f(sa[j][r] - m_i[r]);
                    rs[r] += p;
                    Ps[wv][(qd * 4 + r) * 72 + j * 16 + l16] = f2bf(p);
                }
#pragma unroll
            for (int r = 0; r < 4; ++r) {
                l_i[r] = l_i[r] * al[r] + rsum16(rs[r]);
            }
#pragma unroll
            for (int t = 0; t < 8; ++t)
#pragma unroll
                for (int r = 0; r < 4; ++r) o[t][r] *= al[r];

            // PV
            bf16x8 pf[2];
#pragma unroll
            for (int c = 0; c < 2; ++c)
                pf[c] = *(const bf16x8*)(&Ps[wv][l16 * 72 + c * 32 + qd * 8]);
#pragma unroll
            for (int t = 0; t < 8; ++t)
#pragma unroll
                for (int c = 0; c < 2; ++c) {
                    bf16x8 vf = *(const bf16x8*)(Vs[buf] + (t * 16 + l16) * 72 + c * 32 + qd * 8);
                    o[t] = __builtin_amdgcn_mfma_f32_16x16x32_bf16(pf[c], vf, o[t], 0, 0, 0);
                }

            if (more) {
                storeKV(buf ^ 1, kn, vn);
                __syncthreads();      // tile kt+1 visible; buf reads done
            }
        }

        // epilogue: O / l
        float inv[4];
#pragma unroll
        for (int r = 0; r < 4; ++r) inv[r] = 1.0f / l_i[r];
#pragma unroll
        for (int t = 0; t < 8; ++t)
#pragma unroll
            for (int r = 0; r < 4; ++r) {
                int s = q0 + wv * 16 + qd * 4 + r;
                out[((bS + s) * H_ + h) * 128 + t * 16 + l16] =
                    f2bf(o[t][r] * inv[r]);
            }
    }
}

// ---------------------------------------------------------------------------
extern "C" void kernel_launch(void* const* d_in, const int* in_sizes, int n_in,
                              void* d_out, int out_size, void* d_ws, size_t ws_size,
                              hipStream_t stream)
{
    const float* hs  = (const float*)d_in[0];
    const int*   pos = (const int*)d_in[1];
    const float* Wq  = (const float*)d_in[2];
    const float* Wk  = (const float*)d_in[3];
    const float* Wv  = (const float*)d_in[4];
    const float* Wo  = (const float*)d_in[5];
    const float* qnw = (const float*)d_in[6];
    const float* knw = (const float*)d_in[7];
    float* out = (float*)d_out;
    short* ws  = (short*)d_ws;

    short* hsb   = ws;                         // 4096 x 2048
    short* Wqkvb = hsb + (long)M_ * D_;        // 2432 x 2048 (Wq|Wk|Wv rows)
    short* Wob   = Wqkvb + (long)2432 * D_;    // 2048 x 2048
    short* qk_ws = Wob + (long)D_ * 2048;      // 4096 x 1920 (q | k fused)
    short* vt_ws = qk_ws + (long)M_ * NQK_;    // 512 x 4096  (V^T)
    short* ao_ws = vt_ws + (long)512 * M_;     // 4096 x 2048

    cvt_all<<<17152, 256, 0, stream>>>(hs, Wq, Wk, Wv, Wo, ws);

    gemm_bt<3><<<dim3(M_ / 128, 2432 / 128), 256, 0, stream>>>(
        hsb, Wqkvb, qk_ws, vt_ws, M_, 2432, D_);

    rms_rope<<<(65536 + 16384) / 4, 256, 0, stream>>>(qk_ws, qnw, knw, pos);

    attn<<<dim3(16, 32), 256, 0, stream>>>(qk_ws, vt_ws, ao_ws);

    gemm_bt<2><<<dim3(M_ / 128, D_ / 128), 256, 0, stream>>>(
        ao_ws, Wob, (void*)out, nullptr, M_, D_, H_ * VD_);
}